// Round 9
// baseline (28.052 us; speedup 1.0000x reference)
//
#include <hip/hip_runtime.h>
#include <math.h>

// Chamfer distance, B=8, N=M=4096, D=3, fp32.
// R9: SINGLE-SWEEP split-bf16 MFMA (halves R8's MFMA count).
// One D matrix per batch: D[r][c] = sqA_r + sqB_c - 2 a_r.b_c,
// rows = cloud1 (A-role frags), cols = cloud2 (B-role frags), K-packed as R8.
// Wave fixes its r-tile (A in regs), sweeps 64 c-tiles (half):
//   rowmin: lane-local rmin[16] across sweep; cross-lane reduce ONCE at end
//           (amortized ~1 op/tile) -> atomicMin to dist1u.
//   colmin: per tile 8 v_min3 + ds_min_u32 into block LDS colmin[2048];
//           block partials -> plain stores -> reduce kernel (deterministic).
// No LDS staging, no barriers in hot loop; B streams via L1 (8 waves share
// the same address stream), depth-2 reg prefetch.
// MFMA floor: 131072 mfma * 64 cyc / 1024 SIMD / 2.4GHz = 3.4 us.

typedef __attribute__((ext_vector_type(8)))  short bf16x8;
typedef __attribute__((ext_vector_type(16))) float f32x16;
typedef float f32x2 __attribute__((ext_vector_type(2)));

#define NPTS 4096
#define BATCH 8
#define FRAG_PER_B 8192u   // per batch: 128 tiles * 2 K-halves * 32 rows (uint4)

union FragCast { uint4 u; bf16x8 v; };

__device__ __forceinline__ unsigned short f2bf(float f) {
    unsigned u = __float_as_uint(f);
    return (unsigned short)((u + 0x7FFFu + ((u >> 16) & 1u)) >> 16);
}
__device__ __forceinline__ float bf2f(unsigned short h) {
    return __uint_as_float(((unsigned)h) << 16);
}
__device__ __forceinline__ unsigned pk(unsigned short a, unsigned short b) {
    return (unsigned)a | ((unsigned)b << 16);
}

// ---------------- prep: fa1 (A-role of pcs1), fb2 (B-role of pcs2), dist init
__global__ __launch_bounds__(256) void chamfer_prep(
    const float* __restrict__ pcs1, const float* __restrict__ pcs2,
    uint4* __restrict__ fa1, uint4* __restrict__ fb2,
    unsigned* __restrict__ dist1u)
{
    const int gid = blockIdx.x * 256 + threadIdx.x;  // [0, 32768)
    const int b   = gid >> 12;
    const int pt  = gid & 4095;

    dist1u[gid] = 0x7F800000u;   // +inf

    const int tile = pt >> 5, row = pt & 31;
    const size_t i0 = (size_t)b * FRAG_PER_B + ((size_t)tile * 2 + 0) * 32 + row;
    const size_t i1 = (size_t)b * FRAG_PER_B + ((size_t)tile * 2 + 1) * 32 + row;
    const unsigned short ONE = 0x3F80;

    // A-role from pcs1: hi/lo split of -2*coord + split of |a|^2
    {
        const float* s = pcs1 + ((size_t)b * NPTS + pt) * 3;
        float x = s[0], y = s[1], z = s[2];
        float sq = fmaf(x, x, fmaf(y, y, z * z));
        float m2x = -2.0f * x, m2y = -2.0f * y, m2z = -2.0f * z;
        unsigned short hx = f2bf(m2x), hy = f2bf(m2y), hz = f2bf(m2z);
        unsigned short lx = f2bf(m2x - bf2f(hx));
        unsigned short ly = f2bf(m2y - bf2f(hy));
        unsigned short lz = f2bf(m2z - bf2f(hz));
        unsigned short sh = f2bf(sq);
        unsigned short sl = f2bf(sq - bf2f(sh));
        fa1[i0] = make_uint4(pk(hx, hy), pk(hz, hx), pk(hy, hz), pk(lx, ly));
        fa1[i1] = make_uint4(pk(lz, lx), pk(ly, lz), pk(sh, sl), pk(ONE, ONE));
    }
    // B-role from pcs2: hi/lo split of raw coord + split of |b|^2
    {
        const float* s = pcs2 + ((size_t)b * NPTS + pt) * 3;
        float x = s[0], y = s[1], z = s[2];
        float sq = fmaf(x, x, fmaf(y, y, z * z));
        unsigned short px = f2bf(x), py = f2bf(y), pz = f2bf(z);
        unsigned short qx = f2bf(x - bf2f(px));
        unsigned short qy = f2bf(y - bf2f(py));
        unsigned short qz = f2bf(z - bf2f(pz));
        unsigned short sh = f2bf(sq);
        unsigned short sl = f2bf(sq - bf2f(sh));
        fb2[i0] = make_uint4(pk(px, py), pk(pz, qx), pk(qy, qz), pk(px, py));
        fb2[i1] = make_uint4(pk(pz, qx), pk(qy, qz), pk(ONE, ONE), pk(sh, sl));
    }
}

// ---------------- main: 256 blocks x 512 threads (8 waves) ----------------
// bid: b = bid>>5, rgroup = (bid>>1)&15, chalf = bid&1.
// wave w owns r-tile rt = rgroup*8+w; sweeps c-tiles [chalf*64, chalf*64+64).
__global__ __launch_bounds__(512, 2) void chamfer_mfma(
    const uint4* __restrict__ fa1, const uint4* __restrict__ fb2,
    unsigned* __restrict__ dist1u, unsigned* __restrict__ cpart)
{
    __shared__ unsigned ldscol[2048];   // colmin for this c-half, uint-mapped

    const int bid    = blockIdx.x;
    const int b      = bid >> 5;
    const int rgroup = (bid >> 1) & 15;
    const int chalf  = bid & 1;

    const int tid = threadIdx.x;
    const int w   = tid >> 6;
    const int l   = tid & 63;
    const int hf  = l >> 5;
    const int ln  = l & 31;
    const int rt  = rgroup * 8 + w;

    // init colmin LDS
    {
        uint4* lc4 = (uint4*)ldscol;
        lc4[tid] = make_uint4(0x7F800000u, 0x7F800000u, 0x7F800000u, 0x7F800000u);
    }

    // fixed A-frag (this wave's 32 rows of cloud1)
    FragCast aq;
    aq.u = fa1[(size_t)b * FRAG_PER_B + ((size_t)rt * 2 + hf) * 32 + ln];

    // B stream base: index (ct*2+hf)*32+ln = ct*64 + hf*32 + ln
    const uint4* bptr = fb2 + (size_t)b * FRAG_PER_B
                        + (size_t)chalf * 64 * 64 + hf * 32 + ln;

    const f32x16 cz = {0.f,0.f,0.f,0.f,0.f,0.f,0.f,0.f,
                       0.f,0.f,0.f,0.f,0.f,0.f,0.f,0.f};
    float rmin[16];
#pragma unroll
    for (int i = 0; i < 16; ++i) rmin[i] = 3.4e38f;

    __syncthreads();   // ldscol ready

    // depth-2 prefetch; overread past the half-sweep stays inside d_ws
    uint4 p0 = bptr[0];
    uint4 p1 = bptr[64];
#pragma unroll 2
    for (int ct = 0; ct < 64; ++ct) {
        FragCast bq; bq.u = p0;
        p0 = p1;
        p1 = bptr[(size_t)(ct + 2) * 64];
        f32x16 D = __builtin_amdgcn_mfma_f32_32x32x16_bf16(aq.v, bq.v, cz, 0, 0, 0);

        // rowmin: lane-local accumulate (16 v_min)
#pragma unroll
        for (int i = 0; i < 16; ++i) rmin[i] = fminf(rmin[i], D[i]);

        // colmin: reduce 16 regs (-> v_min3 chain), clamp, ds_min
        float cm = fminf(D[0], D[1]);
#pragma unroll
        for (int i = 1; i < 8; ++i)
            cm = fminf(fminf(cm, D[2 * i]), D[2 * i + 1]);
        cm = fmaxf(cm, 0.0f);
        atomicMin(&ldscol[ct * 32 + ln], __float_as_uint(cm));
    }

    // ---- rowmin epilogue: cross-lane reduce once per sweep ----
#pragma unroll
    for (int off = 1; off < 32; off <<= 1) {
#pragma unroll
        for (int i = 0; i < 16; ++i)
            rmin[i] = fminf(rmin[i], __shfl_xor(rmin[i], off, 64));
    }
    // lane ln<16 takes rmin[ln] (static-select to stay in registers)
    float v = 3.4e38f;
#pragma unroll
    for (int reg = 0; reg < 16; ++reg)
        if (ln == reg) v = rmin[reg];
    if (ln < 16) {
        const int row = (ln & 3) + 8 * (ln >> 2) + 4 * hf;
        atomicMin(&dist1u[(size_t)b * NPTS + rt * 32 + row],
                  __float_as_uint(fmaxf(v, 0.0f)));
    }

    // ---- colmin partial write-out (plain stores, deterministic) ----
    __syncthreads();
    {
        const uint4* lc4 = (const uint4*)ldscol;
        uint4* dst = (uint4*)&cpart[(((size_t)(b * 2 + chalf) * 16 + rgroup) * 2048)];
        dst[tid] = lc4[tid];
    }
}

// ---------------- red1: rows (32768) + cols (32768) -> 128 partials ----------
__global__ __launch_bounds__(256) void chamfer_red1(
    const unsigned* __restrict__ dist1u, const unsigned* __restrict__ cpart,
    float* __restrict__ bpart)
{
    __shared__ float ws[4];
    const int t  = threadIdx.x;
    const int tg = blockIdx.x * 256 + t;       // [0, 32768)
    const int b  = tg >> 12;
    const int c  = tg & 4095;
    const int chalf = c >> 11, cl = c & 2047;

    unsigned m = 0xFFFFFFFFu;
    const unsigned* base = &cpart[(size_t)(b * 2 + chalf) * 16 * 2048 + cl];
#pragma unroll
    for (int rg = 0; rg < 16; ++rg)
        m = min(m, base[(size_t)rg * 2048]);

    float s = sqrtf(__uint_as_float(m)) + sqrtf(__uint_as_float(dist1u[tg]));
#pragma unroll
    for (int off = 1; off < 64; off <<= 1) s += __shfl_xor(s, off, 64);
    if ((t & 63) == 0) ws[t >> 6] = s;
    __syncthreads();
    if (t == 0)
        bpart[blockIdx.x] = ws[0] + ws[1] + ws[2] + ws[3];
}

// ---------------- red2: 128 -> scalar ----------------
__global__ __launch_bounds__(64) void chamfer_red2(
    const float* __restrict__ bpart, float* __restrict__ out)
{
    float v = bpart[threadIdx.x] + bpart[threadIdx.x + 64];
#pragma unroll
    for (int off = 1; off < 64; off <<= 1) v += __shfl_xor(v, off, 64);
    if (threadIdx.x == 0) out[0] = v * (1.0f / 65536.0f);
    // loss = 0.5*(sum1/32768 + sum2/32768) = (sum1+sum2)/65536
}

// ---------------- fallback (proven R5 vector path, 4KB ws) ----------------
#define CPAIRS 1024
#define PA 16
#define RSTRIDE 68

__device__ __forceinline__ f32x2 pk_fma_lo(f32x2 c, f32x2 q, f32x2 acc) {
    f32x2 d;
    asm("v_pk_fma_f32 %0, %1, %2, %3 op_sel:[0,0,0] op_sel_hi:[0,1,1]"
        : "=v"(d) : "v"(c), "v"(q), "v"(acc));
    return d;
}
__device__ __forceinline__ f32x2 pk_fma_hi(f32x2 c, f32x2 q, f32x2 acc) {
    f32x2 d;
    asm("v_pk_fma_f32 %0, %1, %2, %3 op_sel:[1,0,0] op_sel_hi:[1,1,1]"
        : "=v"(d) : "v"(c), "v"(q), "v"(acc));
    return d;
}
__device__ __forceinline__ void vmin3(float& acc, float a, float b) {
    asm("v_min3_f32 %0, %1, %2, %3" : "=v"(acc) : "v"(acc), "v"(a), "v"(b));
}

__global__ __launch_bounds__(256, 4) void chamfer_vec(
    const float* __restrict__ pcs1, const float* __restrict__ pcs2,
    float* __restrict__ partials)
{
    __shared__ float4 lds[2 * CPAIRS];
    float4* bx = lds;
    float4* bz = lds + CPAIRS;

    const int bid = blockIdx.x;
    const int dir = bid >> 9;
    const int b   = (bid >> 6) & 7;
    const int ach = bid & 63;

    const float* A  = dir ? pcs2 : pcs1;
    const float* Bp = dir ? pcs1 : pcs2;
    const float* abase = A  + (size_t)b * NPTS * 3;
    const float* bbase = Bp + (size_t)b * NPTS * 3;

    const int tid = threadIdx.x;
    const int w   = tid >> 6;
    const int l   = tid & 63;

    const int apt = ach * 64 + w * PA;
    f32x2 cx[PA / 2], cy[PA / 2], cz2[PA / 2];
    float tmin[PA];
#pragma unroll
    for (int p2 = 0; p2 < PA / 2; ++p2) {
        const float* s = abase + (size_t)(apt + 2 * p2) * 3;
        cx[p2]  = (f32x2){-2.0f * s[0], -2.0f * s[3]};
        cy[p2]  = (f32x2){-2.0f * s[1], -2.0f * s[4]};
        cz2[p2] = (f32x2){-2.0f * s[2], -2.0f * s[5]};
        tmin[2 * p2] = 3.4e38f; tmin[2 * p2 + 1] = 3.4e38f;
    }

    for (int c = 0; c < 2; ++c) {
        if (c) __syncthreads();
#pragma unroll
        for (int i = 0; i < CPAIRS / 256; ++i) {
            int j  = i * 256 + tid;
            const float* s = bbase + (size_t)(c * CPAIRS + j) * 6;
            float x0 = s[0], y0 = s[1], z0 = s[2];
            float x1 = s[3], y1 = s[4], z1 = s[5];
            bx[j] = make_float4(x0, x1, y0, y1);
            bz[j] = make_float4(z0, z1,
                                fmaf(x0, x0, fmaf(y0, y0, z0 * z0)),
                                fmaf(x1, x1, fmaf(y1, y1, z1 * z1)));
        }
        __syncthreads();
#pragma unroll 4
        for (int t = 0; t < CPAIRS / 64; ++t) {
            float4 X = bx[t * 64 + l];
            float4 Z = bz[t * 64 + l];
            f32x2 qx = (f32x2){X.x, X.y};
            f32x2 qy = (f32x2){X.z, X.w};
            f32x2 qz = (f32x2){Z.x, Z.y};
            f32x2 qw = (f32x2){Z.z, Z.w};
#pragma unroll
            for (int p2 = 0; p2 < PA / 2; ++p2) {
                f32x2 d0 = pk_fma_lo(cz2[p2], qz, qw);
                d0 = pk_fma_lo(cy[p2], qy, d0);
                d0 = pk_fma_lo(cx[p2], qx, d0);
                vmin3(tmin[2 * p2], d0.x, d0.y);
                f32x2 d1 = pk_fma_hi(cz2[p2], qz, qw);
                d1 = pk_fma_hi(cy[p2], qy, d1);
                d1 = pk_fma_hi(cx[p2], qx, d1);
                vmin3(tmin[2 * p2 + 1], d1.x, d1.y);
            }
        }
    }

    __syncthreads();
    float* lds2 = (float*)lds;
#pragma unroll
    for (int p = 0; p < PA; ++p)
        lds2[(w * PA + p) * RSTRIDE + l] = tmin[p];
    __syncthreads();

    if (tid < 64) {
        const int g = tid;
        float m = 3.4e38f;
        const float4* row = (const float4*)&lds2[g * RSTRIDE];
#pragma unroll
        for (int i = 0; i < 16; ++i) {
            float4 v = row[i];
            m = fminf(fminf(m, fminf(v.x, v.y)), fminf(v.z, v.w));
        }
        const int ap = ach * 64 + g;
        float x = abase[ap * 3 + 0], y = abase[ap * 3 + 1], z = abase[ap * 3 + 2];
        float s = sqrtf(fmaxf(fmaf(x, x, fmaf(y, y, z * z)) + m, 0.0f));
#pragma unroll
        for (int off = 1; off < 64; off <<= 1) s += __shfl_xor(s, off, 64);
        if (g == 0) partials[bid] = s;
    }
}

__global__ __launch_bounds__(256) void chamfer_final(
    const float* __restrict__ partials, int n, float scale,
    float* __restrict__ out)
{
    __shared__ float ws[4];
    const int t = threadIdx.x;
    float v = 0.0f;
    for (int i = t; i < n; i += 256) v += partials[i];
#pragma unroll
    for (int off = 1; off < 64; off <<= 1) v += __shfl_xor(v, off, 64);
    if ((t & 63) == 0) ws[t >> 6] = v;
    __syncthreads();
    if (t == 0)
        out[0] = (ws[0] + ws[1] + ws[2] + ws[3]) * scale;
}

extern "C" void kernel_launch(void* const* d_in, const int* in_sizes, int n_in,
                              void* d_out, int out_size, void* d_ws, size_t ws_size,
                              hipStream_t stream) {
    const float* pcs1 = (const float*)d_in[0];
    const float* pcs2 = (const float*)d_in[1];
    float* out = (float*)d_out;

    const size_t MB = 1048576;
    // fa1 1MB | fb2 1MB | dist1u 128KB | cpart 2MB | bpart 512B (+overread slack)
    const size_t need = 2 * MB + 128 * 1024 + 2 * MB + 4096;

    if (ws_size >= need) {
        char* w = (char*)d_ws;
        uint4*    fa1    = (uint4*)(w);
        uint4*    fb2    = (uint4*)(w + 1 * MB);
        unsigned* dist1u = (unsigned*)(w + 2 * MB);
        unsigned* cpart  = (unsigned*)(w + 2 * MB + 128 * 1024);
        float*    bpart  = (float*)(w + 4 * MB + 128 * 1024);

        chamfer_prep<<<dim3(128), dim3(256), 0, stream>>>(
            pcs1, pcs2, fa1, fb2, dist1u);
        chamfer_mfma<<<dim3(256), dim3(512), 0, stream>>>(
            fa1, fb2, dist1u, cpart);
        chamfer_red1<<<dim3(128), dim3(256), 0, stream>>>(dist1u, cpart, bpart);
        chamfer_red2<<<dim3(1),   dim3(64),  0, stream>>>(bpart, out);
    } else {
        float* partials = (float*)d_ws;
        chamfer_vec  <<<dim3(1024), dim3(256), 0, stream>>>(pcs1, pcs2, partials);
        chamfer_final<<<dim3(1),    dim3(256), 0, stream>>>(
            partials, 1024, 1.0f / 65536.0f, out);
    }
}